// Round 15
// baseline (100.187 us; speedup 1.0000x reference)
//
#include <hip/hip_runtime.h>
#include <hip/hip_bf16.h>

typedef unsigned short u16;
typedef unsigned int u32;
typedef __attribute__((ext_vector_type(8))) short short8v;
typedef __attribute__((ext_vector_type(4))) float f32x4;

#define M_ROWS 2048
#define N_COLS 10572
#define K_DIM 512
#define N_PAD 10624
#define SCALE_F 30.0f
#define PI_F 3.14159265358979f
// gemm tiling: 128M x 128N, BK=64, 8 waves (2M x 4N), per-wave 64x32
// 512 thr, ~110 regs, 64KB LDS -> 2 blocks/CU = 16 waves/CU (2x occupancy)
#define NBX 83            // ceil(10572/128)
#define NBY 16            // 2048/128
#define NWG (NBX*NBY)     // 1328 = 8 * 166
#define NSLOT (NBX*4)     // partial-sum slots (4 N-waves per block)

__device__ __forceinline__ u16 bf16rne(float f) {
    u32 u = __float_as_uint(f);
    u += 0x7FFFu + ((u >> 16) & 1u);
    return (u16)(u >> 16);
}

// ---------------- fused prelude: normalize f+w, self-contained gt-dot ----------------
__global__ void k_pre(const float* __restrict__ feat, const float* __restrict__ wgt,
                      const int* __restrict__ label,
                      u16* __restrict__ nfb, u16* __restrict__ nwb,
                      float* __restrict__ cosgt) {
    const int b = blockIdx.x;
    const int lane = threadIdx.x;  // 64
    if (b < M_ROWS) {
        const int i = b;
        const int lab = label[i];
        const float4* pf = (const float4*)feat + (size_t)i * 128 + lane * 2;
        const float4* pw = (const float4*)wgt + (size_t)lab * 128 + lane * 2;
        float4 a = pf[0], c = pf[1], wa = pw[0], wc = pw[1];
        float ssf = a.x*a.x + a.y*a.y + a.z*a.z + a.w*a.w
                  + c.x*c.x + c.y*c.y + c.z*c.z + c.w*c.w;
        float ssw = wa.x*wa.x + wa.y*wa.y + wa.z*wa.z + wa.w*wa.w
                  + wc.x*wc.x + wc.y*wc.y + wc.z*wc.z + wc.w*wc.w;
        float dot = a.x*wa.x + a.y*wa.y + a.z*wa.z + a.w*wa.w
                  + c.x*wc.x + c.y*wc.y + c.z*wc.z + c.w*wc.w;
        for (int d = 32; d; d >>= 1) {
            ssf += __shfl_xor(ssf, d, 64);
            ssw += __shfl_xor(ssw, d, 64);
            dot += __shfl_xor(dot, d, 64);
        }
        if (lane == 0) cosgt[i] = dot / (sqrtf(ssf) * sqrtf(ssw));
        const float inv = 1.0f / sqrtf(ssf);
        uint4 v;
        v.x = (u32)bf16rne(a.x*inv) | ((u32)bf16rne(a.y*inv) << 16);
        v.y = (u32)bf16rne(a.z*inv) | ((u32)bf16rne(a.w*inv) << 16);
        v.z = (u32)bf16rne(c.x*inv) | ((u32)bf16rne(c.y*inv) << 16);
        v.w = (u32)bf16rne(c.z*inv) | ((u32)bf16rne(c.w*inv) << 16);
        ((uint4*)nfb)[(size_t)i * 64 + lane] = v;
    } else {
        const int row = b - M_ROWS;
        if (row >= N_COLS) {
            ((uint4*)nwb)[(size_t)row * 64 + lane] = make_uint4(0, 0, 0, 0);
            return;
        }
        const float4* p = (const float4*)wgt + (size_t)row * 128 + lane * 2;
        float4 a = p[0], c = p[1];
        float ss = a.x*a.x + a.y*a.y + a.z*a.z + a.w*a.w
                 + c.x*c.x + c.y*c.y + c.z*c.z + c.w*c.w;
        for (int d = 32; d; d >>= 1) ss += __shfl_xor(ss, d, 64);
        const float inv = 1.0f / sqrtf(ss);
        uint4 v;
        v.x = (u32)bf16rne(a.x*inv) | ((u32)bf16rne(a.y*inv) << 16);
        v.y = (u32)bf16rne(a.z*inv) | ((u32)bf16rne(a.w*inv) << 16);
        v.z = (u32)bf16rne(c.x*inv) | ((u32)bf16rne(c.y*inv) << 16);
        v.w = (u32)bf16rne(c.z*inv) | ((u32)bf16rne(c.w*inv) << 16);
        ((uint4*)nwb)[(size_t)row * 64 + lane] = v;
    }
}

// ---------------- main bf16 MFMA GEMM: 16 waves/CU config ----------------
// 128x128 tile, BK=64, 8 waves (2Mx4N, 64x32 each). Full-line swizzled staging
// (stage = 4 gload_lds/thread), counted-vmcnt pipeline, C^T epilogue.
// ~110 regs @ launch_bounds(512,4) + 64KB LDS -> 2 blocks/CU = 16 waves/CU.
__global__ void __launch_bounds__(512, 4)
k_gemm(const u16* __restrict__ nfb, const u16* __restrict__ nwb,
       float* __restrict__ cosO, float* __restrict__ mlO,
       float* __restrict__ partial) {
    extern __shared__ __align__(16) u16 lds[];
    // u16 units: A buf0 [0,8192) A buf1 [8192,16384) B buf0 [16384,24576) B buf1 [24576,32768)
    const int tid = threadIdx.x;          // 0..511
    const int lane = tid & 63;
    const int wid = tid >> 6;             // 0..7
    const int wm = wid >> 2, wn = wid & 3;

    // bijective XCD swizzle (1328 = 8*166); consecutive wg on an XCD share bx
    const int lin = blockIdx.x;
    const int wg = (lin & 7) * (NWG / 8) + (lin >> 3);
    const int bx = wg >> 4;               // 0..82
    const int by = wg & 15;               // 0..15
    const int tm = by * 128;
    const int tn = bx * 128;

    // staging source (full-line, pre-swizzled): instr = 8 rows x 128B contiguous
    const int srow = lane >> 3;                 // 0..7
    const int ksrc = (lane & 7) ^ srow;         // swizzled source k-chunk
    const size_t gAoff = (size_t)(tm + wid * 8 + srow) * K_DIM + ksrc * 8;
    const size_t gBoff = (size_t)(tn + wid * 8 + srow) * K_DIM + ksrc * 8;
    const size_t rs64 = (size_t)64 * K_DIM;

    const int kg = lane >> 4, lr = lane & 15;
    const int sw = lr & 7;                      // read-side swizzle (row&7 == lr&7)

    f32x4 acc[4][2] = {};
    short8v af[2][4], bfv[2][2];

    auto stage = [&](int buf, int kt) {
        #pragma unroll
        for (int p = 0; p < 2; ++p) {       // A: 128 rows, 2 instrs/wave
            const u16* gA = nfb + gAoff + p * rs64 + kt * 64;
            u16* lA = &lds[buf * 8192 + (p * 64 + wid * 8) * 64];
            __builtin_amdgcn_global_load_lds(
                (const __attribute__((address_space(1))) void*)gA,
                (__attribute__((address_space(3))) void*)lA, 16, 0, 0);
        }
        #pragma unroll
        for (int p = 0; p < 2; ++p) {       // B: 128 rows
            const u16* gB = nwb + gBoff + p * rs64 + kt * 64;
            u16* lB = &lds[16384 + buf * 8192 + (p * 64 + wid * 8) * 64];
            __builtin_amdgcn_global_load_lds(
                (const __attribute__((address_space(1))) void*)gB,
                (__attribute__((address_space(3))) void*)lB, 16, 0, 0);
        }
    };

    auto ds_reads = [&](int cur) {
        #pragma unroll
        for (int h = 0; h < 2; ++h) {
            const int j = ((h * 4 + kg) ^ sw) * 8;
            #pragma unroll
            for (int mf = 0; mf < 4; ++mf)
                af[h][mf] = *(const short8v*)
                    &lds[cur * 8192 + (wm * 64 + mf * 16 + lr) * 64 + j];
            #pragma unroll
            for (int nf = 0; nf < 2; ++nf)
                bfv[h][nf] = *(const short8v*)
                    &lds[16384 + cur * 8192 + (wn * 32 + nf * 16 + lr) * 64 + j];
        }
    };

    // counted-vmcnt pipeline: stage = 4 loads/thread; keep next stage in flight
    stage(0, 0);
    stage(1, 1);                            // 8 loads/thread outstanding
    #pragma unroll
    for (int kt = 0; kt < 8; ++kt) {
        const int cur = kt & 1;
        if (kt < 7) asm volatile("s_waitcnt vmcnt(4)" ::: "memory");
        else        asm volatile("s_waitcnt vmcnt(0)" ::: "memory");
        __builtin_amdgcn_s_barrier();            // all threads' stage(kt) landed
        __builtin_amdgcn_sched_barrier(0);
        ds_reads(cur);
        asm volatile("s_waitcnt lgkmcnt(0)" ::: "memory");
        __builtin_amdgcn_sched_barrier(0);
        __builtin_amdgcn_s_barrier();            // ALL waves done reading buf[cur]
        __builtin_amdgcn_sched_barrier(0);
        if (kt < 6) stage(cur, kt + 2);          // overlaps MFMAs below
        __builtin_amdgcn_sched_barrier(0);
        #pragma unroll
        for (int h = 0; h < 2; ++h)
            #pragma unroll
            for (int mf = 0; mf < 4; ++mf)
                #pragma unroll
                for (int nf = 0; nf < 2; ++nf)
                    acc[mf][nf] = __builtin_amdgcn_mfma_f32_16x16x32_bf16(
                        bfv[h][nf], af[h][mf], acc[mf][nf], 0, 0, 0);
    }

    // epilogue: dwordx4 stores, 2-shuffle row-sums
    float* prow = partial + (size_t)(bx * 4 + wn) * M_ROWS;
    #pragma unroll
    for (int mf = 0; mf < 4; ++mf) {
        const int row = tm + wm * 64 + mf * 16 + lr;
        float rs = 0.f;
        #pragma unroll
        for (int nf = 0; nf < 2; ++nf) {
            const int col = tn + wn * 32 + nf * 16 + kg * 4;   // multiple of 4
            const f32x4 v = acc[mf][nf];
            if (col < N_COLS) {                                 // whole vec in/out
                const size_t idx = (size_t)row * N_COLS + col;  // 16B-aligned
                f32x4 ml;
                ml[0] = SCALE_F * v[0]; ml[1] = SCALE_F * v[1];
                ml[2] = SCALE_F * v[2]; ml[3] = SCALE_F * v[3];
                *(f32x4*)&cosO[idx] = v;
                *(f32x4*)&mlO[idx] = ml;
                rs += __expf(ml[0]) + __expf(ml[1]) + __expf(ml[2]) + __expf(ml[3]);
            }
        }
        rs += __shfl_xor(rs, 16, 64);
        rs += __shfl_xor(rs, 32, 64);
        if (kg == 0) prow[row] = rs;
    }
}

// ---------------- fused post: theta stats + margins + gt patch + rowsum + cosLast ----
__global__ void k_post(const float* __restrict__ cosgt, const float* __restrict__ partial,
                       const int* __restrict__ label, const float* __restrict__ cosO,
                       float* __restrict__ mlO, float* __restrict__ rowsum,
                       float* __restrict__ cosLast) {
    const int t = threadIdx.x;           // 256
    const int lane = t & 63, w = t >> 6; // 4 waves
    __shared__ float smx[4], smn[4];
    __shared__ double ssm[4];
    __shared__ float bc[3];
    // redundant full reduction over all 2048 rows (8 values per thread)
    float mx = -1e30f, mn = 1e30f;
    double sm = 0.0;
    #pragma unroll
    for (int k = 0; k < 8; ++k) {
        const float c = fminf(fmaxf(cosgt[t + k * 256], -1.f), 1.f);
        const float th = acosf(c) * (180.f / PI_F);
        mx = fmaxf(mx, th); mn = fminf(mn, th); sm += (double)th;
    }
    for (int d = 32; d; d >>= 1) {
        mx = fmaxf(mx, __shfl_xor(mx, d, 64));
        mn = fminf(mn, __shfl_xor(mn, d, 64));
        sm += __shfl_xor(sm, d, 64);
    }
    if (lane == 0) { smx[w] = mx; smn[w] = mn; ssm[w] = sm; }
    __syncthreads();
    if (t == 0) {
        float MX = smx[0], MN = smn[0]; double SM = ssm[0];
        for (int j = 1; j < 4; ++j) {
            MX = fmaxf(MX, smx[j]); MN = fminf(MN, smn[j]); SM += ssm[j];
        }
        const float avg = (float)(SM / 2048.0);
        bc[0] = avg;
        bc[1] = (MX < 90.f) ? (90.f - avg) * (PI_F / 180.f) : 0.f;  // mhi
        bc[2] = MN * (PI_F / 180.f);                                 // mlo
    }
    __syncthreads();
    const float avg = bc[0], mhi = bc[1], mlo = bc[2];
    const int row = blockIdx.x * 256 + t;
    // rowsum reduce
    float s = 0.f;
    for (int j = 0; j < NSLOT; ++j) s += partial[(size_t)j * M_ROWS + row];
    rowsum[row] = s;
    // cosLast gather
    const int labL = label[M_ROWS - 1];
    cosLast[row] = cosO[(size_t)row * N_COLS + labL];
    // margin + gt patch
    const float cg = fminf(fmaxf(cosgt[row], -1.f), 1.f);
    const float th = acosf(cg) * (180.f / PI_F);
    const float m = (th > avg) ? mhi : mlo;
    const bool inside = cg > -cosf(m);
    const float add = inside ? m : 0.f;
    const float ext = inside ? 0.f : (-m * sinf(m));
    mlO[(size_t)row * N_COLS + label[row]] = SCALE_F * (cosf(acosf(cg) + add) + ext);
}

// ---------------- final scalar stats ----------------
__global__ void k_final(const float* __restrict__ rowsum, const float* __restrict__ cosLast,
                        float* __restrict__ outS) {
    const int t = threadIdx.x;           // 1024
    const int lane = t & 63, w = t >> 6;
    __shared__ float smin[16], smax[16];
    __shared__ double ssum[16], sbs[16];
    double psum = 0.0, bsum = 0.0;
    float mn = 1e30f, mx = -1e30f;
    #pragma unroll
    for (int k = 0; k < 2; ++k) {
        const int r = t + k * 1024;
        const float e = expf(SCALE_F * cosLast[r]);
        const float rsv = rowsum[r];
        const float p = e / rsv;
        psum += (double)p;
        bsum += (double)rsv - (double)e;
        mn = fminf(mn, p); mx = fmaxf(mx, p);
    }
    for (int d = 32; d; d >>= 1) {
        mn = fminf(mn, __shfl_xor(mn, d, 64));
        mx = fmaxf(mx, __shfl_xor(mx, d, 64));
        psum += __shfl_xor(psum, d, 64);
        bsum += __shfl_xor(bsum, d, 64);
    }
    if (lane == 0) { smin[w] = mn; smax[w] = mx; ssum[w] = psum; sbs[w] = bsum; }
    __syncthreads();
    if (t == 0) {
        float MN = smin[0], MX = smax[0]; double PS = ssum[0], BS = sbs[0];
        for (int j = 1; j < 16; ++j) {
            MN = fminf(MN, smin[j]); MX = fmaxf(MX, smax[j]);
            PS += ssum[j]; BS += sbs[j];
        }
        outS[0] = (float)(PS / 2048.0);                 // avg_p
        outS[1] = MN;                                   // min_p
        outS[2] = MX;                                   // max_p
        const double mb = BS / 2048.0 / (double)(N_COLS - 1);
        outS[3] = (float)(acos(log(mb) / 30.0) * (180.0 / 3.14159265358979));  // B_avg
    }
}

extern "C" void kernel_launch(void* const* d_in, const int* in_sizes, int n_in,
                              void* d_out, int out_size, void* d_ws, size_t ws_size,
                              hipStream_t stream) {
    const float* feat = (const float*)d_in[0];
    const int* label = (const int*)d_in[1];
    const float* weights = (const float*)d_in[2];

    char* ws = (char*)d_ws;
    u16* nfb      = (u16*)(ws);                       // 2,097,152 B
    u16* nwb      = (u16*)(ws + 2097152);             // 10,878,976 B -> 12,976,128
    float* cosgt  = (float*)(ws + 13026816);          // 8192
    float* rowsum = (float*)(ws + 13043200);          // 8192
    float* cosLast= (float*)(ws + 13051392);          // 8192
    float* partial= (float*)(ws + 13059584);          // 332*2048*4 = 2,719,744

    float* cosO = (float*)d_out;
    float* mlO  = cosO + (size_t)M_ROWS * N_COLS;
    float* outS = cosO + (size_t)2 * M_ROWS * N_COLS;

    k_pre<<<M_ROWS + N_PAD, 64, 0, stream>>>(feat, weights, label, nfb, nwb, cosgt);
    k_gemm<<<NWG, 512, 65536, stream>>>(nfb, nwb, cosO, mlO, partial);
    k_post<<<8, 256, 0, stream>>>(cosgt, partial, label, cosO, mlO, rowsum, cosLast);
    k_final<<<1, 1024, 0, stream>>>(rowsum, cosLast, outS);
}

// Round 16
// 77.027 us; speedup vs baseline: 1.3007x; 1.3007x over previous
//
#include <hip/hip_runtime.h>
#include <hip/hip_bf16.h>

typedef unsigned short u16;
typedef unsigned int u32;
typedef __attribute__((ext_vector_type(8))) short short8v;
typedef __attribute__((ext_vector_type(4))) float f32x4;

#define M_ROWS 2048
#define N_COLS 10572
#define K_DIM 512
#define N_PAD 10752       // 42 * 256
#define SCALE_F 30.0f
#define PI_F 3.14159265358979f
// gemm tiling: 128M x 256N (1KB write span/row), BK=64, 8 waves (2M x 4N), per-wave 64x64
#define NBX2 42           // ceil(10572/256)
#define NBY 16            // 2048/128
#define NWG (NBX2*NBY)    // 672 = 8 * 84
#define NSLOT (NBX2*4)    // partial-sum slots (4 N-waves per block)

__device__ __forceinline__ u16 bf16rne(float f) {
    u32 u = __float_as_uint(f);
    u += 0x7FFFu + ((u >> 16) & 1u);
    return (u16)(u >> 16);
}

// ---------------- fused prelude: normalize f+w, self-contained gt-dot ----------------
__global__ void k_pre(const float* __restrict__ feat, const float* __restrict__ wgt,
                      const int* __restrict__ label,
                      u16* __restrict__ nfb, u16* __restrict__ nwb,
                      float* __restrict__ cosgt) {
    const int b = blockIdx.x;
    const int lane = threadIdx.x;  // 64
    if (b < M_ROWS) {
        const int i = b;
        const int lab = label[i];
        const float4* pf = (const float4*)feat + (size_t)i * 128 + lane * 2;
        const float4* pw = (const float4*)wgt + (size_t)lab * 128 + lane * 2;
        float4 a = pf[0], c = pf[1], wa = pw[0], wc = pw[1];
        float ssf = a.x*a.x + a.y*a.y + a.z*a.z + a.w*a.w
                  + c.x*c.x + c.y*c.y + c.z*c.z + c.w*c.w;
        float ssw = wa.x*wa.x + wa.y*wa.y + wa.z*wa.z + wa.w*wa.w
                  + wc.x*wc.x + wc.y*wc.y + wc.z*wc.z + wc.w*wc.w;
        float dot = a.x*wa.x + a.y*wa.y + a.z*wa.z + a.w*wa.w
                  + c.x*wc.x + c.y*wc.y + c.z*wc.z + c.w*wc.w;
        for (int d = 32; d; d >>= 1) {
            ssf += __shfl_xor(ssf, d, 64);
            ssw += __shfl_xor(ssw, d, 64);
            dot += __shfl_xor(dot, d, 64);
        }
        if (lane == 0) cosgt[i] = dot / (sqrtf(ssf) * sqrtf(ssw));
        const float inv = 1.0f / sqrtf(ssf);
        uint4 v;
        v.x = (u32)bf16rne(a.x*inv) | ((u32)bf16rne(a.y*inv) << 16);
        v.y = (u32)bf16rne(a.z*inv) | ((u32)bf16rne(a.w*inv) << 16);
        v.z = (u32)bf16rne(c.x*inv) | ((u32)bf16rne(c.y*inv) << 16);
        v.w = (u32)bf16rne(c.z*inv) | ((u32)bf16rne(c.w*inv) << 16);
        ((uint4*)nfb)[(size_t)i * 64 + lane] = v;
    } else {
        const int row = b - M_ROWS;
        if (row >= N_COLS) {
            ((uint4*)nwb)[(size_t)row * 64 + lane] = make_uint4(0, 0, 0, 0);
            return;
        }
        const float4* p = (const float4*)wgt + (size_t)row * 128 + lane * 2;
        float4 a = p[0], c = p[1];
        float ss = a.x*a.x + a.y*a.y + a.z*a.z + a.w*a.w
                 + c.x*c.x + c.y*c.y + c.z*c.z + c.w*c.w;
        for (int d = 32; d; d >>= 1) ss += __shfl_xor(ss, d, 64);
        const float inv = 1.0f / sqrtf(ss);
        uint4 v;
        v.x = (u32)bf16rne(a.x*inv) | ((u32)bf16rne(a.y*inv) << 16);
        v.y = (u32)bf16rne(a.z*inv) | ((u32)bf16rne(a.w*inv) << 16);
        v.z = (u32)bf16rne(c.x*inv) | ((u32)bf16rne(c.y*inv) << 16);
        v.w = (u32)bf16rne(c.z*inv) | ((u32)bf16rne(c.w*inv) << 16);
        ((uint4*)nwb)[(size_t)row * 64 + lane] = v;
    }
}

// ---------------- main bf16 MFMA GEMM: 128M x 256N tile (1KB write spans) ----------------
// 8 waves (2Mx4N, per-wave 64x64 = R14's proven geometry). BK=64 dbuf, 96KB LDS,
// full-line swizzled staging (6 gload_lds/thread/stage), counted vmcnt(6), C^T epilogue.
// Per output row each block now writes 1KB contiguous (vs 512B) -> better DRAM page use.
__global__ void __launch_bounds__(512, 2)
k_gemm(const u16* __restrict__ nfb, const u16* __restrict__ nwb,
       float* __restrict__ cosO, float* __restrict__ mlO,
       float* __restrict__ partial) {
    extern __shared__ __align__(16) u16 lds[];
    // u16 units: A buf0 [0,8192) A buf1 [8192,16384)
    //            B buf0 [16384,32768) B buf1 [32768,49152)   (96KB total)
    const int tid = threadIdx.x;          // 0..511
    const int lane = tid & 63;
    const int wid = tid >> 6;             // 0..7
    const int wm = wid >> 2, wn = wid & 3;

    // bijective XCD swizzle (672 = 8*84); consecutive wg on an XCD share bx
    const int lin = blockIdx.x;
    const int wg = (lin & 7) * (NWG / 8) + (lin >> 3);
    const int bx = wg >> 4;               // 0..41  (N tile, 256 cols)
    const int by = wg & 15;               // 0..15  (M tile, 128 rows)
    const int tm = by * 128;
    const int tn = bx * 256;

    // staging source (full-line, pre-swizzled): instr = 8 rows x 128B contiguous
    const int srow = lane >> 3;                 // 0..7
    const int ksrc = (lane & 7) ^ srow;         // swizzled source k-chunk
    const size_t gAoff = (size_t)(tm + wid * 8 + srow) * K_DIM + ksrc * 8;
    const size_t gBoff = (size_t)(tn + wid * 8 + srow) * K_DIM + ksrc * 8;
    const size_t rs64 = (size_t)64 * K_DIM;

    const int kg = lane >> 4, lr = lane & 15;
    const int sw = lr & 7;                      // read-side swizzle (row&7 == lr&7)

    f32x4 acc[4][4] = {};
    short8v af[2][4], bfv[2][4];

    auto stage = [&](int buf, int kt) {
        #pragma unroll
        for (int p = 0; p < 2; ++p) {       // A: 128 rows, 2 instrs/wave
            const u16* gA = nfb + gAoff + p * rs64 + kt * 64;
            u16* lA = &lds[buf * 8192 + (p * 64 + wid * 8) * 64];
            __builtin_amdgcn_global_load_lds(
                (const __attribute__((address_space(1))) void*)gA,
                (__attribute__((address_space(3))) void*)lA, 16, 0, 0);
        }
        #pragma unroll
        for (int p = 0; p < 4; ++p) {       // B: 256 rows, 4 instrs/wave
            const u16* gB = nwb + gBoff + p * rs64 + kt * 64;
            u16* lB = &lds[16384 + buf * 16384 + (p * 64 + wid * 8) * 64];
            __builtin_amdgcn_global_load_lds(
                (const __attribute__((address_space(1))) void*)gB,
                (__attribute__((address_space(3))) void*)lB, 16, 0, 0);
        }
    };

    auto ds_reads = [&](int cur) {
        #pragma unroll
        for (int h = 0; h < 2; ++h) {
            const int j = ((h * 4 + kg) ^ sw) * 8;
            #pragma unroll
            for (int mf = 0; mf < 4; ++mf)
                af[h][mf] = *(const short8v*)
                    &lds[cur * 8192 + (wm * 64 + mf * 16 + lr) * 64 + j];
            #pragma unroll
            for (int nf = 0; nf < 4; ++nf)
                bfv[h][nf] = *(const short8v*)
                    &lds[16384 + cur * 16384 + (wn * 64 + nf * 16 + lr) * 64 + j];
        }
    };

    // counted-vmcnt pipeline: stage = 6 loads/thread; keep next stage in flight
    stage(0, 0);
    stage(1, 1);                            // 12 loads/thread outstanding
    #pragma unroll
    for (int kt = 0; kt < 8; ++kt) {
        const int cur = kt & 1;
        if (kt < 7) asm volatile("s_waitcnt vmcnt(6)" ::: "memory");
        else        asm volatile("s_waitcnt vmcnt(0)" ::: "memory");
        __builtin_amdgcn_s_barrier();            // all threads' stage(kt) landed
        __builtin_amdgcn_sched_barrier(0);
        ds_reads(cur);
        asm volatile("s_waitcnt lgkmcnt(0)" ::: "memory");
        __builtin_amdgcn_sched_barrier(0);
        __builtin_amdgcn_s_barrier();            // ALL waves done reading buf[cur]
        __builtin_amdgcn_sched_barrier(0);
        if (kt < 6) stage(cur, kt + 2);          // overlaps MFMAs below
        __builtin_amdgcn_sched_barrier(0);
        #pragma unroll
        for (int h = 0; h < 2; ++h)
            #pragma unroll
            for (int mf = 0; mf < 4; ++mf)
                #pragma unroll
                for (int nf = 0; nf < 4; ++nf)
                    acc[mf][nf] = __builtin_amdgcn_mfma_f32_16x16x32_bf16(
                        bfv[h][nf], af[h][mf], acc[mf][nf], 0, 0, 0);
    }

    // epilogue: dwordx4 stores, 2-shuffle row-sums; tile writes 1KB contiguous per row
    float* prow = partial + (size_t)(bx * 4 + wn) * M_ROWS;
    #pragma unroll
    for (int mf = 0; mf < 4; ++mf) {
        const int row = tm + wm * 64 + mf * 16 + lr;
        float rs = 0.f;
        #pragma unroll
        for (int nf = 0; nf < 4; ++nf) {
            const int col = tn + wn * 64 + nf * 16 + kg * 4;   // multiple of 4
            const f32x4 v = acc[mf][nf];
            if (col < N_COLS) {                                 // whole vec in/out
                const size_t idx = (size_t)row * N_COLS + col;  // 16B-aligned
                f32x4 ml;
                ml[0] = SCALE_F * v[0]; ml[1] = SCALE_F * v[1];
                ml[2] = SCALE_F * v[2]; ml[3] = SCALE_F * v[3];
                *(f32x4*)&cosO[idx] = v;
                *(f32x4*)&mlO[idx] = ml;
                rs += __expf(ml[0]) + __expf(ml[1]) + __expf(ml[2]) + __expf(ml[3]);
            }
        }
        rs += __shfl_xor(rs, 16, 64);
        rs += __shfl_xor(rs, 32, 64);
        if (kg == 0) prow[row] = rs;
    }
}

// ---------------- fused post: theta stats + margins + gt patch + rowsum + cosLast ----
__global__ void k_post(const float* __restrict__ cosgt, const float* __restrict__ partial,
                       const int* __restrict__ label, const float* __restrict__ cosO,
                       float* __restrict__ mlO, float* __restrict__ rowsum,
                       float* __restrict__ cosLast) {
    const int t = threadIdx.x;           // 256
    const int lane = t & 63, w = t >> 6; // 4 waves
    __shared__ float smx[4], smn[4];
    __shared__ double ssm[4];
    __shared__ float bc[3];
    // redundant full reduction over all 2048 rows (8 values per thread)
    float mx = -1e30f, mn = 1e30f;
    double sm = 0.0;
    #pragma unroll
    for (int k = 0; k < 8; ++k) {
        const float c = fminf(fmaxf(cosgt[t + k * 256], -1.f), 1.f);
        const float th = acosf(c) * (180.f / PI_F);
        mx = fmaxf(mx, th); mn = fminf(mn, th); sm += (double)th;
    }
    for (int d = 32; d; d >>= 1) {
        mx = fmaxf(mx, __shfl_xor(mx, d, 64));
        mn = fminf(mn, __shfl_xor(mn, d, 64));
        sm += __shfl_xor(sm, d, 64);
    }
    if (lane == 0) { smx[w] = mx; smn[w] = mn; ssm[w] = sm; }
    __syncthreads();
    if (t == 0) {
        float MX = smx[0], MN = smn[0]; double SM = ssm[0];
        for (int j = 1; j < 4; ++j) {
            MX = fmaxf(MX, smx[j]); MN = fminf(MN, smn[j]); SM += ssm[j];
        }
        const float avg = (float)(SM / 2048.0);
        bc[0] = avg;
        bc[1] = (MX < 90.f) ? (90.f - avg) * (PI_F / 180.f) : 0.f;  // mhi
        bc[2] = MN * (PI_F / 180.f);                                 // mlo
    }
    __syncthreads();
    const float avg = bc[0], mhi = bc[1], mlo = bc[2];
    const int row = blockIdx.x * 256 + t;
    // rowsum reduce
    float s = 0.f;
    for (int j = 0; j < NSLOT; ++j) s += partial[(size_t)j * M_ROWS + row];
    rowsum[row] = s;
    // cosLast gather
    const int labL = label[M_ROWS - 1];
    cosLast[row] = cosO[(size_t)row * N_COLS + labL];
    // margin + gt patch
    const float cg = fminf(fmaxf(cosgt[row], -1.f), 1.f);
    const float th = acosf(cg) * (180.f / PI_F);
    const float m = (th > avg) ? mhi : mlo;
    const bool inside = cg > -cosf(m);
    const float add = inside ? m : 0.f;
    const float ext = inside ? 0.f : (-m * sinf(m));
    mlO[(size_t)row * N_COLS + label[row]] = SCALE_F * (cosf(acosf(cg) + add) + ext);
}

// ---------------- final scalar stats ----------------
__global__ void k_final(const float* __restrict__ rowsum, const float* __restrict__ cosLast,
                        float* __restrict__ outS) {
    const int t = threadIdx.x;           // 1024
    const int lane = t & 63, w = t >> 6;
    __shared__ float smin[16], smax[16];
    __shared__ double ssum[16], sbs[16];
    double psum = 0.0, bsum = 0.0;
    float mn = 1e30f, mx = -1e30f;
    #pragma unroll
    for (int k = 0; k < 2; ++k) {
        const int r = t + k * 1024;
        const float e = expf(SCALE_F * cosLast[r]);
        const float rsv = rowsum[r];
        const float p = e / rsv;
        psum += (double)p;
        bsum += (double)rsv - (double)e;
        mn = fminf(mn, p); mx = fmaxf(mx, p);
    }
    for (int d = 32; d; d >>= 1) {
        mn = fminf(mn, __shfl_xor(mn, d, 64));
        mx = fmaxf(mx, __shfl_xor(mx, d, 64));
        psum += __shfl_xor(psum, d, 64);
        bsum += __shfl_xor(bsum, d, 64);
    }
    if (lane == 0) { smin[w] = mn; smax[w] = mx; ssum[w] = psum; sbs[w] = bsum; }
    __syncthreads();
    if (t == 0) {
        float MN = smin[0], MX = smax[0]; double PS = ssum[0], BS = sbs[0];
        for (int j = 1; j < 16; ++j) {
            MN = fminf(MN, smin[j]); MX = fmaxf(MX, smax[j]);
            PS += ssum[j]; BS += sbs[j];
        }
        outS[0] = (float)(PS / 2048.0);                 // avg_p
        outS[1] = MN;                                   // min_p
        outS[2] = MX;                                   // max_p
        const double mb = BS / 2048.0 / (double)(N_COLS - 1);
        outS[3] = (float)(acos(log(mb) / 30.0) * (180.0 / 3.14159265358979));  // B_avg
    }
}

extern "C" void kernel_launch(void* const* d_in, const int* in_sizes, int n_in,
                              void* d_out, int out_size, void* d_ws, size_t ws_size,
                              hipStream_t stream) {
    const float* feat = (const float*)d_in[0];
    const int* label = (const int*)d_in[1];
    const float* weights = (const float*)d_in[2];

    char* ws = (char*)d_ws;
    u16* nfb      = (u16*)(ws);                       // 2,097,152 B
    u16* nwb      = (u16*)(ws + 2097152);             // 10752*512*2 = 11,010,048 -> 13,107,200
    float* cosgt  = (float*)(ws + 13107200);          // 8192
    float* rowsum = (float*)(ws + 13115392);          // 8192
    float* cosLast= (float*)(ws + 13123584);          // 8192
    float* partial= (float*)(ws + 13131776);          // 168*2048*4 = 1,376,256

    float* cosO = (float*)d_out;
    float* mlO  = cosO + (size_t)M_ROWS * N_COLS;
    float* outS = cosO + (size_t)2 * M_ROWS * N_COLS;

    k_pre<<<M_ROWS + N_PAD, 64, 0, stream>>>(feat, weights, label, nfb, nwb, cosgt);
    k_gemm<<<NWG, 512, 98304, stream>>>(nfb, nwb, cosO, mlO, partial);
    k_post<<<8, 256, 0, stream>>>(cosgt, partial, label, cosO, mlO, rowsum, cosLast);
    k_final<<<1, 1024, 0, stream>>>(rowsum, cosLast, outS);
}